// Round 3
// baseline (165.586 us; speedup 1.0000x reference)
//
#include <hip/hip_runtime.h>
#include <stdint.h>

// ---------- types ----------
typedef __bf16 bf16x8 __attribute__((ext_vector_type(8)));
typedef float f32x4 __attribute__((ext_vector_type(4)));
typedef float float4v __attribute__((ext_vector_type(4)));
typedef unsigned short u16x8 __attribute__((ext_vector_type(8)));

// round-to-nearest-even fp32 -> bf16
__device__ __forceinline__ unsigned short f2bf(float f) {
    unsigned u = __float_as_uint(f);
    u += 0x7fffu + ((u >> 16) & 1u);
    return (unsigned short)(u >> 16);
}

// fast stable softplus: max(x,0) + log(1+exp(-|x|))
__device__ __forceinline__ float softplus(float x) {
    return fmaxf(x, 0.0f) + __logf(1.0f + __expf(-fabsf(x)));
}

// async global->LDS, 16B per lane (gfx950). LDS dest must be wave-uniform
// base + lane*16 (lane-ordered, contiguous).
__device__ __forceinline__ void gl_lds16(const void* gptr, void* lptr) {
    auto g = reinterpret_cast<const __attribute__((address_space(1))) void*>(
        reinterpret_cast<uintptr_t>(gptr));
    auto l = reinterpret_cast<__attribute__((address_space(3))) void*>(
        reinterpret_cast<uintptr_t>(lptr));
    __builtin_amdgcn_global_load_lds(g, l, 16, 0, 0);
}

// ---------- fused prep: input f32->bf16  AND  w = mu + softplus(rho)*eps ----
__global__ void prep_kernel(const float* __restrict__ in,
                            const float* __restrict__ mu,
                            const float* __restrict__ rho,
                            const float* __restrict__ eps,
                            unsigned short* __restrict__ in_bf,
                            unsigned short* __restrict__ w_bf,
                            int nIn8, int nW8) {
    int i = blockIdx.x * blockDim.x + threadIdx.x;
    if (i < nIn8) {
        const float4v* p = (const float4v*)in + (size_t)i * 2;
        float4v a = p[0], b = p[1];
        u16x8 r;
        r[0] = f2bf(a[0]); r[1] = f2bf(a[1]); r[2] = f2bf(a[2]); r[3] = f2bf(a[3]);
        r[4] = f2bf(b[0]); r[5] = f2bf(b[1]); r[6] = f2bf(b[2]); r[7] = f2bf(b[3]);
        ((u16x8*)in_bf)[i] = r;
    } else {
        int j = i - nIn8;
        if (j >= nW8) return;
        const float4v* pm = (const float4v*)mu  + (size_t)j * 2;
        const float4v* pr = (const float4v*)rho + (size_t)j * 2;
        const float4v* pe = (const float4v*)eps + (size_t)j * 2;
        float4v m0 = pm[0], m1 = pm[1];
        float4v r0 = pr[0], r1 = pr[1];
        float4v e0 = pe[0], e1 = pe[1];
        u16x8 r;
        r[0] = f2bf(m0[0] + softplus(r0[0]) * e0[0]);
        r[1] = f2bf(m0[1] + softplus(r0[1]) * e0[1]);
        r[2] = f2bf(m0[2] + softplus(r0[2]) * e0[2]);
        r[3] = f2bf(m0[3] + softplus(r0[3]) * e0[3]);
        r[4] = f2bf(m1[0] + softplus(r1[0]) * e1[0]);
        r[5] = f2bf(m1[1] + softplus(r1[1]) * e1[1]);
        r[6] = f2bf(m1[2] + softplus(r1[2]) * e1[2]);
        r[7] = f2bf(m1[3] + softplus(r1[3]) * e1[3]);
        ((u16x8*)w_bf)[j] = r;
    }
}

// ---------- GEMM: C[M,N] = A[M,K] * B[N,K]^T + bias, bf16 in / f32 out -----
// DEEP-PIPELINED chunk ring (T3+T4+T5):
//   - 128x128 C-tile, 256 threads = 4 waves, wave tile 64x64 (FLOP/LDS-byte
//     2x the old 64x32 -> LDS-read-pipe ceiling ~60% MfmaUtil).
//   - K split into chunks of 32; 4-slot LDS ring (16 KB/chunk, 64 KB total,
//     2 blocks/CU). 3 chunks ALWAYS in flight; counted s_waitcnt vmcnt(12)
//     (= 3 chunks x 4 loads/thread) -- never drained to 0 in the main loop,
//     so global->LDS latency (~600-900 cyc) is covered by ~3 chunk windows
//     instead of the old depth-1 prefetch (~200 cyc cover -> 32% MfmaUtil).
//   - Raw s_barrier (no compiler vmcnt(0) drain). Barrier pair per chunk:
//     B_a after vmcnt (chunk i readable by all), B_b after lgkmcnt(0)
//     (chunk i's ds_reads complete -> slot reusable by stage at iter i+1).
//   - sched_barrier(0) pins each inline-asm waitcnt in program order
//     (hardening per methodology rule #18 -- compiler may otherwise
//     schedule ops across inline-asm waits).
//   - s_setprio(1) around the MFMA cluster (T5).
//   - Tail: staged chunk index clamps to the last chunk so the vmcnt count
//     stays uniform; redundant loads are L2-hits.
//   - LDS layout [row][32] bf16 = 64 B row stride: fragment ds_read_b128
//     spreads lanes evenly over all bank-quads (8 lanes each = the b128
//     inherent minimum) -> no conflicts, no swizzle needed (and
//     global_load_lds requires the linear layout).
#define BM 128
#define BN 128
#define KC 32
#define SLOT_U 8192   // ushorts per ring slot: A 128*32 + B 128*32

__global__ __launch_bounds__(256, 2)
void gemm_bt_kernel(const unsigned short* __restrict__ A,   // [M,K] bf16
                    const unsigned short* __restrict__ B,   // [N,K] bf16
                    const float* __restrict__ bias,         // [N]
                    float* __restrict__ C,                  // [M,N] f32
                    int M, int N, int K) {
    __shared__ unsigned short lds[4][SLOT_U];   // 64 KB ring

    const int t      = threadIdx.x;
    const int lane   = t & 63;
    const int wave   = t >> 6;          // 0..3
    const int lane16 = lane & 15;
    const int quad   = lane >> 4;       // 0..3
    const int wm     = wave & 1;        // wave row: 0..1 (64 rows each)
    const int wn     = wave >> 1;       // wave col: 0..1 (64 cols each)

    const int m0 = blockIdx.y * BM;
    const int n0 = blockIdx.x * BN;

    // staging: chunk = A[128][32] + B[128][32] = 1024 x 16B, 256 thr -> 4 ea.
    // slot layout is linear row-major, so LDS offset = t*8 ushorts per group.
    const int r  = t >> 2;              // 0..63
    const int kg = (t & 3) * 8;         // k-element offset of this 16B piece

    const unsigned short* a0 = A + (size_t)(m0 + r)      * K + kg;
    const unsigned short* a1 = A + (size_t)(m0 + 64 + r) * K + kg;
    const unsigned short* b0 = B + (size_t)(n0 + r)      * K + kg;
    const unsigned short* b1 = B + (size_t)(n0 + 64 + r) * K + kg;

    f32x4 acc[4][4] = {};

    auto stage = [&](int slot, int kc) {
        const int k0 = kc * KC;
        gl_lds16(a0 + k0, &lds[slot][t * 8]);
        gl_lds16(a1 + k0, &lds[slot][2048 + t * 8]);
        gl_lds16(b0 + k0, &lds[slot][4096 + t * 8]);
        gl_lds16(b1 + k0, &lds[slot][6144 + t * 8]);
    };

    const int nchunk = K / KC;          // 64
    stage(0, 0);
    stage(1, 1);
    stage(2, 2);                        // 12 loads in flight

    // fragment read offsets (ushort idx), constant per thread
    const int ra = (wm * 64 + lane16) * KC + quad * 8;
    const int rb = 4096 + (wn * 64 + lane16) * KC + quad * 8;

#pragma unroll 4
    for (int i = 0; i < nchunk; ++i) {
        const int slot = i & 3;
        // issue stage for chunk i+3 into slot (i-1)&3 -- released by B_b(i-1)
        stage((i + 3) & 3, (i + 3 < nchunk) ? (i + 3) : (nchunk - 1));
        // chunk i landed for this wave (16 outstanding -> wait oldest 4)
        asm volatile("s_waitcnt vmcnt(12)" ::: "memory");
        __builtin_amdgcn_sched_barrier(0);
        __builtin_amdgcn_s_barrier();               // B_a: chunk i ready block-wide
        const unsigned short* ls = lds[slot];
        bf16x8 af[4], bf[4];
#pragma unroll
        for (int mi = 0; mi < 4; ++mi)
            af[mi] = *(const bf16x8*)(ls + ra + mi * 16 * KC);
#pragma unroll
        for (int ni = 0; ni < 4; ++ni)
            bf[ni] = *(const bf16x8*)(ls + rb + ni * 16 * KC);
        __builtin_amdgcn_s_setprio(1);
#pragma unroll
        for (int mi = 0; mi < 4; ++mi)
#pragma unroll
            for (int ni = 0; ni < 4; ++ni)
                acc[mi][ni] = __builtin_amdgcn_mfma_f32_16x16x32_bf16(
                    af[mi], bf[ni], acc[mi][ni], 0, 0, 0);
        __builtin_amdgcn_s_setprio(0);
        // ds_reads of chunk i fully complete before releasing the slot
        asm volatile("s_waitcnt lgkmcnt(0)" ::: "memory");
        __builtin_amdgcn_sched_barrier(0);
        __builtin_amdgcn_s_barrier();               // B_b: slot i&3 reusable
    }

    // epilogue: C/D layout col=lane&15, row=quad*4+reg (m89-verified)
    float bv[4];
#pragma unroll
    for (int ni = 0; ni < 4; ++ni)
        bv[ni] = bias[n0 + wn * 64 + ni * 16 + lane16];

#pragma unroll
    for (int mi = 0; mi < 4; ++mi) {
        const int rbase = m0 + wm * 64 + mi * 16 + quad * 4;
#pragma unroll
        for (int ni = 0; ni < 4; ++ni) {
            const int col = n0 + wn * 64 + ni * 16 + lane16;
#pragma unroll
            for (int rr = 0; rr < 4; ++rr)
                C[(size_t)(rbase + rr) * N + col] = acc[mi][ni][rr] + bv[ni];
        }
    }
}

extern "C" void kernel_launch(void* const* d_in, const int* in_sizes, int n_in,
                              void* d_out, int out_size, void* d_ws, size_t ws_size,
                              hipStream_t stream) {
    const float* input = (const float*)d_in[0];
    const float* mu    = (const float*)d_in[1];
    const float* rho   = (const float*)d_in[2];
    const float* eps   = (const float*)d_in[3];
    const float* bias  = (const float*)d_in[4];
    float* out = (float*)d_out;

    const int OUT = in_sizes[4];              // 2048
    const int IN  = in_sizes[1] / OUT;        // 2048
    const int M   = in_sizes[0] / IN;         // 4096

    unsigned short* in_bf = (unsigned short*)d_ws;                 // M*IN bf16
    unsigned short* w_bf  = in_bf + (size_t)M * IN;                // OUT*IN bf16

    const int nIn8 = (M * IN) / 8;
    const int nW8  = (OUT * IN) / 8;
    prep_kernel<<<dim3((nIn8 + nW8 + 255) / 256), 256, 0, stream>>>(
        input, mu, rho, eps, in_bf, w_bf, nIn8, nW8);

    gemm_bt_kernel<<<dim3(OUT / BN, M / BM), 256, 0, stream>>>(
        in_bf, w_bf, bias, out, M, OUT, IN);
}